// Round 6
// baseline (701.475 us; speedup 1.0000x reference)
//
#include <hip/hip_runtime.h>
#include <hip/hip_bf16.h>

typedef __attribute__((ext_vector_type(8))) short short8;
typedef __attribute__((ext_vector_type(4))) float floatx4;
typedef unsigned short u16;

#define T_SZ 609
#define K1V  4872   // valid K of flattened LSTM output (609*8)
#define K1P  4896   // padded to multiple of 32
#define RD   4      // LDS ring depth (slots)

static __device__ __forceinline__ u16 f2bf(float f) {
    union { float f; unsigned u; } a; a.f = f;
    unsigned r = a.u + 0x7FFF + ((a.u >> 16) & 1);   // round-to-nearest-even
    return (u16)(r >> 16);
}

// async global->LDS, 16B per lane; LDS dest = wave-uniform base + lane*16
static __device__ __forceinline__ void gload_lds16(const u16* g, u16* l) {
    __builtin_amdgcn_global_load_lds(
        (const __attribute__((address_space(1))) void*)g,
        (__attribute__((address_space(3))) void*)l, 16, 0, 0);
}

#define WG_LOAD(p)     __hip_atomic_load((p), __ATOMIC_ACQUIRE, __HIP_MEMORY_SCOPE_WORKGROUP)
#define WG_STORE(p, v) __hip_atomic_store((p), (v), __ATOMIC_RELEASE, __HIP_MEMORY_SCOPE_WORKGROUP)

// ==================== fp32 -> bf16 conversion (plain) ====================
__global__ __launch_bounds__(256) void cvt_kernel(const float* __restrict__ s,
                                                  u16* __restrict__ d, int n) {
    int i = (blockIdx.x * 256 + threadIdx.x) * 8;
    if (i < n) {
        float4 a = *(const float4*)(s + i);
        float4 b = *(const float4*)(s + i + 4);
        u16 o[8] = { f2bf(a.x), f2bf(a.y), f2bf(a.z), f2bf(a.w),
                     f2bf(b.x), f2bf(b.y), f2bf(b.z), f2bf(b.w) };
        *(uint4*)(d + i) = *(const uint4*)o;
    }
}

// ============== fp32 -> bf16 with row/col zero padding ==============
__global__ __launch_bounds__(256) void cvt_pad_kernel(const float* __restrict__ s,
                                                      u16* __restrict__ d,
                                                      int R, int K, int Kp) {
    int chunk = blockIdx.x * 256 + threadIdx.x;
    int cpr = Kp >> 3;
    int r = chunk / cpr;
    int c = (chunk - r * cpr) << 3;
    u16 o[8] = {0, 0, 0, 0, 0, 0, 0, 0};
    if (r < R && c < K) {
        const float* p = s + (size_t)r * K + c;
        float4 a = *(const float4*)p;
        float4 b = *(const float4*)(p + 4);
        o[0] = f2bf(a.x); o[1] = f2bf(a.y); o[2] = f2bf(a.z); o[3] = f2bf(a.w);
        o[4] = f2bf(b.x); o[5] = f2bf(b.y); o[6] = f2bf(b.z); o[7] = f2bf(b.w);
    }
    *(uint4*)&d[(size_t)r * Kp + c] = *(const uint4*)o;
}

// ============================ LSTM (wave-specialized, lane=unit) ============================
// Block = 8 batch rows, 3 waves; wave w runs layer w for all 8 rows over all t.
// Lane = row*8 + unit: each lane computes ALL FOUR gate preacts of its (row,unit)
// locally (4 independent 16-FMA chains) -> zero gather shuffles. Recurrent h and
// previous-layer h are read from depth-RD LDS rings (2x ds_read_b128, row-broadcast).
// Handoff flags: acquire/release counters, workgroup scope (waves co-resident).
// L1's input dot (x-part) is computed one step ahead (recurrence-independent).
__global__ __launch_bounds__(192) void lstm3_kernel(
    const float* __restrict__ x,
    const float* __restrict__ Wih1, const float* __restrict__ Whh1,
    const float* __restrict__ bih1, const float* __restrict__ bhh1,
    const float* __restrict__ Wih2, const float* __restrict__ Whh2,
    const float* __restrict__ bih2, const float* __restrict__ bhh2,
    const float* __restrict__ Wih3, const float* __restrict__ Whh3,
    const float* __restrict__ bih3, const float* __restrict__ bhh3,
    u16* __restrict__ A1)
{
    __shared__ __align__(16) float xs[8 * T_SZ * 5];          // 97,440 B
    __shared__ __align__(16) float r1[RD * 64], r2[RD * 64], r3[RD * 64];
    __shared__ int s_p1, s_p2, s_c2, s_c3;

    const int tid = threadIdx.x;
    const int b0  = blockIdx.x * 8;

    // stage x: 8 rows contiguous in global, float4-aligned (97,440 % 16 == 0)
    const float4* xg4 = (const float4*)(x + (size_t)b0 * (T_SZ * 5));
    float4* xs4 = (float4*)xs;
    for (int i = tid; i < (8 * T_SZ * 5) / 4; i += 192) xs4[i] = xg4[i];
    if (tid == 0) { s_p1 = 0; s_p2 = 0; s_c2 = 0; s_c3 = 0; }
    // zero the K padding columns of A1 (ws is poisoned each launch): 8 rows x 24 cols
    {
        int r = tid / 24, c = tid - r * 24;
        if (r < 8) A1[(size_t)(b0 + r) * K1P + K1V + c] = 0;
    }
    __syncthreads();

    const int lane = tid & 63, wid = tid >> 6;
    const int row  = lane >> 3;        // local batch row 0..7
    const int jj   = lane & 7;         // hidden unit this lane owns
    const int rb   = row * 8;          // ring offset of this row

    // all-local gate math: pre0..3 = i,f,g,o preacts -> h
    auto gates = [&](float p0, float p1, float p2, float p3, float& c) -> float {
        float ei = __expf(-p0); float i_ = __fdividef(1.f, 1.f + ei);
        float ef = __expf(-p1); float f_ = __fdividef(1.f, 1.f + ef);
        float eg = __expf(-2.f * __builtin_fabsf(p2));
        float g_ = __builtin_copysignf((1.f - eg) * __fdividef(1.f, 1.f + eg), p2);
        float eo = __expf(-p3); float o_ = __fdividef(1.f, 1.f + eo);
        c = __builtin_fmaf(f_, c, i_ * g_);
        float ec = __expf(-2.f * __builtin_fabsf(c));
        float th = (1.f - ec) * __fdividef(1.f, 1.f + ec);
        return o_ * __builtin_copysignf(th, c);
    };

    if (wid == 0) {
        // ---------------- L1 wave ----------------
        float wi[4][5], wh[4][8], bs[4];
#pragma unroll
        for (int g = 0; g < 4; ++g) {
#pragma unroll
            for (int k = 0; k < 5; ++k) wi[g][k] = Wih1[(g * 8 + jj) * 5 + k];
#pragma unroll
            for (int k = 0; k < 8; ++k) wh[g][k] = Whh1[(g * 8 + jj) * 8 + k];
            bs[g] = bih1[g * 8 + jj] + bhh1[g * 8 + jj];
        }
        const float* xr = &xs[row * (T_SZ * 5)];
        float c = 0.f;
        float xa0, xa1, xa2, xa3;
        {   // x-dot for t=0
            float v0 = xr[0], v1 = xr[1], v2 = xr[2], v3 = xr[3], v4 = xr[4];
            xa0 = bs[0]; xa1 = bs[1]; xa2 = bs[2]; xa3 = bs[3];
            xa0 = __builtin_fmaf(wi[0][0], v0, xa0); xa1 = __builtin_fmaf(wi[1][0], v0, xa1);
            xa2 = __builtin_fmaf(wi[2][0], v0, xa2); xa3 = __builtin_fmaf(wi[3][0], v0, xa3);
            xa0 = __builtin_fmaf(wi[0][1], v1, xa0); xa1 = __builtin_fmaf(wi[1][1], v1, xa1);
            xa2 = __builtin_fmaf(wi[2][1], v1, xa2); xa3 = __builtin_fmaf(wi[3][1], v1, xa3);
            xa0 = __builtin_fmaf(wi[0][2], v2, xa0); xa1 = __builtin_fmaf(wi[1][2], v2, xa1);
            xa2 = __builtin_fmaf(wi[2][2], v2, xa2); xa3 = __builtin_fmaf(wi[3][2], v2, xa3);
            xa0 = __builtin_fmaf(wi[0][3], v3, xa0); xa1 = __builtin_fmaf(wi[1][3], v3, xa1);
            xa2 = __builtin_fmaf(wi[2][3], v3, xa2); xa3 = __builtin_fmaf(wi[3][3], v3, xa3);
            xa0 = __builtin_fmaf(wi[0][4], v4, xa0); xa1 = __builtin_fmaf(wi[1][4], v4, xa1);
            xa2 = __builtin_fmaf(wi[2][4], v4, xa2); xa3 = __builtin_fmaf(wi[3][4], v4, xa3);
        }
        for (int t = 0; t < T_SZ; ++t) {
            float p0 = xa0, p1 = xa1, p2 = xa2, p3 = xa3;
            if (t > 0) {
                const float* hp = &r1[((t - 1) & (RD - 1)) * 64 + rb];
                float4 h0 = *(const float4*)hp;
                float4 h1 = *(const float4*)(hp + 4);
#pragma unroll
                for (int g = 0; g < 4; ++g) {
                    float* pp = (g == 0) ? &p0 : (g == 1) ? &p1 : (g == 2) ? &p2 : &p3;
                    float a = *pp;
                    a = __builtin_fmaf(wh[g][0], h0.x, a); a = __builtin_fmaf(wh[g][1], h0.y, a);
                    a = __builtin_fmaf(wh[g][2], h0.z, a); a = __builtin_fmaf(wh[g][3], h0.w, a);
                    a = __builtin_fmaf(wh[g][4], h1.x, a); a = __builtin_fmaf(wh[g][5], h1.y, a);
                    a = __builtin_fmaf(wh[g][6], h1.z, a); a = __builtin_fmaf(wh[g][7], h1.w, a);
                    *pp = a;
                }
            }
            // prefetch next x-dot (independent of recurrence chain)
            if (t + 1 < T_SZ) {
                const float* xn = xr + (t + 1) * 5;
                float v0 = xn[0], v1 = xn[1], v2 = xn[2], v3 = xn[3], v4 = xn[4];
                xa0 = bs[0]; xa1 = bs[1]; xa2 = bs[2]; xa3 = bs[3];
                xa0 = __builtin_fmaf(wi[0][0], v0, xa0); xa1 = __builtin_fmaf(wi[1][0], v0, xa1);
                xa2 = __builtin_fmaf(wi[2][0], v0, xa2); xa3 = __builtin_fmaf(wi[3][0], v0, xa3);
                xa0 = __builtin_fmaf(wi[0][1], v1, xa0); xa1 = __builtin_fmaf(wi[1][1], v1, xa1);
                xa2 = __builtin_fmaf(wi[2][1], v1, xa2); xa3 = __builtin_fmaf(wi[3][1], v1, xa3);
                xa0 = __builtin_fmaf(wi[0][2], v2, xa0); xa1 = __builtin_fmaf(wi[1][2], v2, xa1);
                xa2 = __builtin_fmaf(wi[2][2], v2, xa2); xa3 = __builtin_fmaf(wi[3][2], v2, xa3);
                xa0 = __builtin_fmaf(wi[0][3], v3, xa0); xa1 = __builtin_fmaf(wi[1][3], v3, xa1);
                xa2 = __builtin_fmaf(wi[2][3], v3, xa2); xa3 = __builtin_fmaf(wi[3][3], v3, xa3);
                xa0 = __builtin_fmaf(wi[0][4], v4, xa0); xa1 = __builtin_fmaf(wi[1][4], v4, xa1);
                xa2 = __builtin_fmaf(wi[2][4], v4, xa2); xa3 = __builtin_fmaf(wi[3][4], v4, xa3);
            }
            float h = gates(p0, p1, p2, p3, c);
            if (t >= RD) while (WG_LOAD(&s_c2) < t - (RD - 1)) {}
            r1[(t & (RD - 1)) * 64 + rb + jj] = h;
            if (lane == 0) WG_STORE(&s_p1, t + 1);
        }
    } else if (wid == 1) {
        // ---------------- L2 wave ----------------
        float wi[4][8], wh[4][8], bs[4];
#pragma unroll
        for (int g = 0; g < 4; ++g) {
#pragma unroll
            for (int k = 0; k < 8; ++k) {
                wi[g][k] = Wih2[(g * 8 + jj) * 8 + k];
                wh[g][k] = Whh2[(g * 8 + jj) * 8 + k];
            }
            bs[g] = bih2[g * 8 + jj] + bhh2[g * 8 + jj];
        }
        float c = 0.f;
        for (int t = 0; t < T_SZ; ++t) {
            while (WG_LOAD(&s_p1) < t + 1) {}
            const float* ip = &r1[(t & (RD - 1)) * 64 + rb];
            float4 i0 = *(const float4*)ip;
            float4 i1 = *(const float4*)(ip + 4);
            float p0 = bs[0], p1 = bs[1], p2 = bs[2], p3 = bs[3];
#pragma unroll
            for (int g = 0; g < 4; ++g) {
                float* pp = (g == 0) ? &p0 : (g == 1) ? &p1 : (g == 2) ? &p2 : &p3;
                float a = *pp;
                a = __builtin_fmaf(wi[g][0], i0.x, a); a = __builtin_fmaf(wi[g][1], i0.y, a);
                a = __builtin_fmaf(wi[g][2], i0.z, a); a = __builtin_fmaf(wi[g][3], i0.w, a);
                a = __builtin_fmaf(wi[g][4], i1.x, a); a = __builtin_fmaf(wi[g][5], i1.y, a);
                a = __builtin_fmaf(wi[g][6], i1.z, a); a = __builtin_fmaf(wi[g][7], i1.w, a);
                *pp = a;
            }
            if (lane == 0) WG_STORE(&s_c2, t + 1);   // release: reads above drained
            if (t > 0) {
                const float* hp = &r2[((t - 1) & (RD - 1)) * 64 + rb];
                float4 h0 = *(const float4*)hp;
                float4 h1 = *(const float4*)(hp + 4);
#pragma unroll
                for (int g = 0; g < 4; ++g) {
                    float* pp = (g == 0) ? &p0 : (g == 1) ? &p1 : (g == 2) ? &p2 : &p3;
                    float a = *pp;
                    a = __builtin_fmaf(wh[g][0], h0.x, a); a = __builtin_fmaf(wh[g][1], h0.y, a);
                    a = __builtin_fmaf(wh[g][2], h0.z, a); a = __builtin_fmaf(wh[g][3], h0.w, a);
                    a = __builtin_fmaf(wh[g][4], h1.x, a); a = __builtin_fmaf(wh[g][5], h1.y, a);
                    a = __builtin_fmaf(wh[g][6], h1.z, a); a = __builtin_fmaf(wh[g][7], h1.w, a);
                    *pp = a;
                }
            }
            float h = gates(p0, p1, p2, p3, c);
            if (t >= RD) while (WG_LOAD(&s_c3) < t - (RD - 1)) {}
            r2[(t & (RD - 1)) * 64 + rb + jj] = h;
            if (lane == 0) WG_STORE(&s_p2, t + 1);
        }
    } else {
        // ---------------- L3 wave ----------------
        float wi[4][8], wh[4][8], bs[4];
#pragma unroll
        for (int g = 0; g < 4; ++g) {
#pragma unroll
            for (int k = 0; k < 8; ++k) {
                wi[g][k] = Wih3[(g * 8 + jj) * 8 + k];
                wh[g][k] = Whh3[(g * 8 + jj) * 8 + k];
            }
            bs[g] = bih3[g * 8 + jj] + bhh3[g * 8 + jj];
        }
        float c = 0.f;
        u16* outp = A1 + (size_t)(b0 + row) * K1P;
        for (int t = 0; t < T_SZ; ++t) {
            while (WG_LOAD(&s_p2) < t + 1) {}
            const float* ip = &r2[(t & (RD - 1)) * 64 + rb];
            float4 i0 = *(const float4*)ip;
            float4 i1 = *(const float4*)(ip + 4);
            float p0 = bs[0], p1 = bs[1], p2 = bs[2], p3 = bs[3];
#pragma unroll
            for (int g = 0; g < 4; ++g) {
                float* pp = (g == 0) ? &p0 : (g == 1) ? &p1 : (g == 2) ? &p2 : &p3;
                float a = *pp;
                a = __builtin_fmaf(wi[g][0], i0.x, a); a = __builtin_fmaf(wi[g][1], i0.y, a);
                a = __builtin_fmaf(wi[g][2], i0.z, a); a = __builtin_fmaf(wi[g][3], i0.w, a);
                a = __builtin_fmaf(wi[g][4], i1.x, a); a = __builtin_fmaf(wi[g][5], i1.y, a);
                a = __builtin_fmaf(wi[g][6], i1.z, a); a = __builtin_fmaf(wi[g][7], i1.w, a);
                *pp = a;
            }
            if (lane == 0) WG_STORE(&s_c3, t + 1);
            if (t > 0) {
                const float* hp = &r3[((t - 1) & (RD - 1)) * 64 + rb];
                float4 h0 = *(const float4*)hp;
                float4 h1 = *(const float4*)(hp + 4);
#pragma unroll
                for (int g = 0; g < 4; ++g) {
                    float* pp = (g == 0) ? &p0 : (g == 1) ? &p1 : (g == 2) ? &p2 : &p3;
                    float a = *pp;
                    a = __builtin_fmaf(wh[g][0], h0.x, a); a = __builtin_fmaf(wh[g][1], h0.y, a);
                    a = __builtin_fmaf(wh[g][2], h0.z, a); a = __builtin_fmaf(wh[g][3], h0.w, a);
                    a = __builtin_fmaf(wh[g][4], h1.x, a); a = __builtin_fmaf(wh[g][5], h1.y, a);
                    a = __builtin_fmaf(wh[g][6], h1.z, a); a = __builtin_fmaf(wh[g][7], h1.w, a);
                    *pp = a;
                }
            }
            float h = gates(p0, p1, p2, p3, c);
            r3[(t & (RD - 1)) * 64 + rb + jj] = h;   // private ring, no flags
            outp[t * 8 + jj] = f2bf(h);
        }
    }
}

// ============================ bf16 NT GEMM + bias + (ReLU) ============================
// C[m][n] = act( sum_k A[m][k]*B[n][k] + bias[n] ). 16x16x32 bf16 MFMA, BK=32,
// m97-style async staging: global_load_lds dwordx4, unpadded LDS (row = 32 u16).
template<int BM, int BN, bool RELU, bool NGUARD, bool OUTF32>
__global__ __launch_bounds__(256) void gemm_bt(
    const u16* __restrict__ A, int lda,
    const u16* __restrict__ B, int ldb,
    const float* __restrict__ bias,
    void* __restrict__ Cv, int ldc, int N, int K)
{
    constexpr int WM = BM / 2, WN = BN / 2;
    constexpr int TM = WM / 16, TN = WN / 16;
    __shared__ u16 As[BM * 32];
    __shared__ u16 Bs[BN * 32];

    const int tid = threadIdx.x;
    const int bm  = blockIdx.y * BM;
    const int bn  = blockIdx.x * BN;
    const int l   = tid & 63, w = tid >> 6;
    const int wr  = w >> 1, wc = w & 1;
    const int lr  = l & 15, q = l >> 4;
    const int lrow = l >> 2;            // staging: lane -> row within 16-row group
    const int lcol = (l & 3) << 3;      // staging: lane -> 8-elem chunk

    floatx4 acc[TM][TN];
#pragma unroll
    for (int i = 0; i < TM; ++i)
#pragma unroll
        for (int j = 0; j < TN; ++j) acc[i][j] = (floatx4){0.f, 0.f, 0.f, 0.f};

    const u16* Ab = A + (size_t)bm * lda;
    const u16* Bb = B + (size_t)bn * ldb;

    for (int k0 = 0; k0 < K; k0 += 32) {
#pragma unroll
        for (int i = 0; i < BM / 64; ++i) {
            int r0 = w * (BM / 4) + i * 16;
            gload_lds16(Ab + (size_t)(r0 + lrow) * lda + k0 + lcol, &As[r0 * 32]);
        }
#pragma unroll
        for (int i = 0; i < BN / 64; ++i) {
            int r0 = w * (BN / 4) + i * 16;
            gload_lds16(Bb + (size_t)(r0 + lrow) * ldb + k0 + lcol, &Bs[r0 * 32]);
        }
        __syncthreads();

        short8 fa[TM], fb[TN];
#pragma unroll
        for (int i = 0; i < TM; ++i)
            fa[i] = *(const short8*)&As[(wr * WM + i * 16 + lr) * 32 + q * 8];
#pragma unroll
        for (int j = 0; j < TN; ++j)
            fb[j] = *(const short8*)&Bs[(wc * WN + j * 16 + lr) * 32 + q * 8];
#pragma unroll
        for (int i = 0; i < TM; ++i)
#pragma unroll
            for (int j = 0; j < TN; ++j)
                acc[i][j] = __builtin_amdgcn_mfma_f32_16x16x32_bf16(fa[i], fb[j], acc[i][j], 0, 0, 0);
        __syncthreads();
    }

    // epilogue: C/D layout col = lane&15, row = (lane>>4)*4 + reg  [m89/m91]
#pragma unroll
    for (int j = 0; j < TN; ++j) {
        int n = bn + wc * WN + j * 16 + lr;
        bool nok = (!NGUARD) || (n < N);
        float bv = nok ? bias[n] : 0.f;
#pragma unroll
        for (int i = 0; i < TM; ++i) {
            int m0r = bm + wr * WM + i * 16 + q * 4;
#pragma unroll
            for (int r = 0; r < 4; ++r) {
                float vv = acc[i][j][r] + bv;
                if (RELU) vv = fmaxf(vv, 0.f);
                if (nok) {
                    size_t idx = (size_t)(m0r + r) * ldc + n;
                    if (OUTF32) ((float*)Cv)[idx] = vv;
                    else        ((u16*)Cv)[idx] = f2bf(vv);
                }
            }
        }
    }
}

// ============================ launch ============================
extern "C" void kernel_launch(void* const* d_in, const int* in_sizes, int n_in,
                              void* d_out, int out_size, void* d_ws, size_t ws_size,
                              hipStream_t stream)
{
    const float* x    = (const float*)d_in[0];
    const float* Wih1 = (const float*)d_in[1];
    const float* Whh1 = (const float*)d_in[2];
    const float* bih1 = (const float*)d_in[3];
    const float* bhh1 = (const float*)d_in[4];
    const float* Wih2 = (const float*)d_in[5];
    const float* Whh2 = (const float*)d_in[6];
    const float* bih2 = (const float*)d_in[7];
    const float* bhh2 = (const float*)d_in[8];
    const float* Wih3 = (const float*)d_in[9];
    const float* Whh3 = (const float*)d_in[10];
    const float* bih3 = (const float*)d_in[11];
    const float* bhh3 = (const float*)d_in[12];
    const float* W1 = (const float*)d_in[13];
    const float* b1 = (const float*)d_in[14];
    const float* W2 = (const float*)d_in[15];
    const float* b2 = (const float*)d_in[16];
    const float* W3 = (const float*)d_in[17];
    const float* b3 = (const float*)d_in[18];

    // ws layout (bf16 elems): A1[2048][4896], A2[2048][4096], A3[2048][1024],
    // W1b[4096][4896] (K-padded), W2b[1024][4096], W3b[640][1024] (row-padded). ~91 MB.
    u16* A1  = (u16*)d_ws;
    u16* A2  = A1  + (size_t)2048 * K1P;
    u16* A3  = A2  + (size_t)2048 * 4096;
    u16* W1b = A3  + (size_t)2048 * 1024;
    u16* W2b = W1b + (size_t)4096 * K1P;
    u16* W3b = W2b + (size_t)1024 * 4096;

    // weight conversions fp32 -> bf16 (zero-padded where needed)
    cvt_pad_kernel<<<9792, 256, 0, stream>>>(W1, W1b, 4096, K1V, K1P);
    cvt_kernel<<<2048, 256, 0, stream>>>(W2, W2b, 1024 * 4096);
    cvt_pad_kernel<<<320, 256, 0, stream>>>(W3, W3b, T_SZ, 1024, 1024);

    lstm3_kernel<<<256, 192, 0, stream>>>(x, Wih1, Whh1, bih1, bhh1,
                                          Wih2, Whh2, bih2, bhh2,
                                          Wih3, Whh3, bih3, bhh3, A1);

    // L1: [2048,4896] x W1b[4096,4896] -> relu -> A2 [2048,4096]  (bf16 out)
    gemm_bt<128, 128, true, false, false><<<dim3(32, 16), 256, 0, stream>>>(
        A1, K1P, W1b, K1P, b1, A2, 4096, 4096, K1P);

    // L2: [2048,4096] x W2b[1024,4096] -> relu -> A3 [2048,1024]  (bf16 out)
    gemm_bt<64, 128, true, false, false><<<dim3(8, 32), 256, 0, stream>>>(
        A2, 4096, W2b, 4096, b2, A3, 1024, 1024, 4096);

    // L3: [2048,1024] x W3b[640,1024] -> d_out [2048,609]  (fp32 out, store N-guard)
    gemm_bt<64, 128, false, true, true><<<dim3(5, 32), 256, 0, stream>>>(
        A3, 1024, W3b, 1024, b3, d_out, T_SZ, T_SZ, 1024);
}